// Round 19
// baseline (185.875 us; speedup 1.0000x reference)
//
#include <hip/hip_runtime.h>
#include <float.h>

#define DIM     64
#define NCODES  65536
#define KC      8
#define NQ      8192        // B*S
#define KROW    80          // bf16 row: 64 data + c2_hi + c2_lo + zeros (5 mfma k-steps)
#define CS      32          // collect code splits (r9/r18-measured optimum)
#define CHUNK   (NCODES/CS) // 2048 codes per block-scan (collect)
#define NITER   (CHUNK/32)  // 64 tiles
#define NVIEW   64          // collect views per query (CS * 2 lane-halves)
#define CAP     12          // candidate slots per (query,view)
#define DELTA   0.75f       // collect margin: >= 2 * worst bf16-vs-exact score error
#define MAXSUR  512         // rescore capacity (8 x 64)
// pass-A subset: threshold needs only >=8 distinct codes' scores
#define CSA     32          // pass-A chunks
#define CHUNKA  256         // codes per pass-A wave-scan (subset = 8192 codes)
#define NITERA  (CHUNKA/32) // 8 tiles
#define NVIEWA  64          // pass-A views per query (CSA * 2 lane-halves)

typedef __bf16 bf16x8 __attribute__((ext_vector_type(8)));
typedef float  f32x16 __attribute__((ext_vector_type(16)));
typedef unsigned short u16x8 __attribute__((ext_vector_type(8)));

#define ZERO16 {0,0,0,0, 0,0,0,0, 0,0,0,0, 0,0,0,0}

static __device__ __forceinline__ unsigned short f2bf(float f) {
    unsigned u = __float_as_uint(f);
    u += 0x7FFFu + ((u >> 16) & 1u);
    return (unsigned short)(u >> 16);
}

#define RJ(j) (((j) & 3) + 8 * ((j) >> 2))   // C/D row for acc reg j (HW-verified)

// ---------------- kernel 1: fused conversion (codebook + x) ----------------
__global__ __launch_bounds__(256) void k_conv(const float* __restrict__ cb,
                                              const float* __restrict__ x,
                                              unsigned short* __restrict__ cbb,
                                              unsigned short* __restrict__ xb) {
    if (blockIdx.x < NCODES / 256) {
        int n = blockIdx.x * 256 + threadIdx.x;
        const float4* src = (const float4*)(cb + (size_t)n * DIM);
        unsigned short* dst = cbb + (size_t)n * KROW;
        float s = 0.f;
#pragma unroll
        for (int c = 0; c < 8; ++c) {
            float4 f0 = src[2 * c], f1 = src[2 * c + 1];
            s = fmaf(f0.x, f0.x, s); s = fmaf(f0.y, f0.y, s);
            s = fmaf(f0.z, f0.z, s); s = fmaf(f0.w, f0.w, s);
            s = fmaf(f1.x, f1.x, s); s = fmaf(f1.y, f1.y, s);
            s = fmaf(f1.z, f1.z, s); s = fmaf(f1.w, f1.w, s);
            u16x8 o;
            o[0] = f2bf(2.f * f0.x); o[1] = f2bf(2.f * f0.y);
            o[2] = f2bf(2.f * f0.z); o[3] = f2bf(2.f * f0.w);
            o[4] = f2bf(2.f * f1.x); o[5] = f2bf(2.f * f1.y);
            o[6] = f2bf(2.f * f1.z); o[7] = f2bf(2.f * f1.w);
            *(u16x8*)(dst + c * 8) = o;
        }
        unsigned short hi = f2bf(s);
        float hif = __uint_as_float(((unsigned)hi) << 16);
        unsigned short lo = f2bf(s - hif);
        u16x8 p = { (unsigned short)(hi ^ 0x8000u), (unsigned short)(lo ^ 0x8000u),
                    0, 0, 0, 0, 0, 0 };
        *(u16x8*)(dst + 64) = p;
        u16x8 z = {0, 0, 0, 0, 0, 0, 0, 0};
        *(u16x8*)(dst + 72) = z;
    } else {
        int n = (blockIdx.x - NCODES / 256) * 256 + threadIdx.x;
        const float4* src = (const float4*)(x + (size_t)n * DIM);
        unsigned short* dst = xb + (size_t)n * KROW;
#pragma unroll
        for (int c = 0; c < 8; ++c) {
            float4 f0 = src[2 * c], f1 = src[2 * c + 1];
            u16x8 o;
            o[0] = f2bf(f0.x); o[1] = f2bf(f0.y); o[2] = f2bf(f0.z); o[3] = f2bf(f0.w);
            o[4] = f2bf(f1.x); o[5] = f2bf(f1.y); o[6] = f2bf(f1.z); o[7] = f2bf(f1.w);
            *(u16x8*)(dst + c * 8) = o;
        }
        u16x8 p = {0x3F80u, 0x3F80u, 0, 0, 0, 0, 0, 0};   // 1.0, 1.0
        *(u16x8*)(dst + 64) = p;
        u16x8 z = {0, 0, 0, 0, 0, 0, 0, 0};
        *(u16x8*)(dst + 72) = z;
    }
}

// max of 16 acc values, nested-triple form so clang fuses to v_max3 (8 ops)
__device__ __forceinline__ float tmax16(const f32x16& a) {
    const float m0 = fmaxf(fmaxf(a[0],  a[1]),  a[2]);
    const float m1 = fmaxf(fmaxf(a[3],  a[4]),  a[5]);
    const float m2 = fmaxf(fmaxf(a[6],  a[7]),  a[8]);
    const float m3 = fmaxf(fmaxf(a[9],  a[10]), a[11]);
    const float m4 = fmaxf(fmaxf(a[12], a[13]), a[14]);
    const float n0 = fmaxf(fmaxf(m0, m1), m2);
    const float n1 = fmaxf(fmaxf(m3, m4), a[15]);
    return fmaxf(n0, n1);
}

// ---------------- kernel 2: pass A — per-view top-1 on an 8K-code subset ---
// grid 1024. XCD swizzle: all same-chunk blocks on one XCD (chunk L2-resident).
// r15/r18 register structure (2 buffers, 2 query-sets, launch_bounds(,4)).
// THRESHOLD SAFETY: T = 8th-best of 64 DISJOINT views' maxima = 8th-best of
// >=8 distinct codes' bf16 scores => T <= g_s8(global) <= f_s8 + eps. Any
// exact-top-8 member m has g(m) >= f_s8 - eps >= T - 2eps; DELTA >= 2eps.
// Subset only loosens T (more survivors) - never unsafe.
__global__ __launch_bounds__(256, 4) void k_scanA(const unsigned short* __restrict__ cbb_,
                                                  const unsigned short* __restrict__ xb_,
                                                  float* __restrict__ top1) {
    const __bf16* cbv = (const __bf16*)cbb_;
    const __bf16* xbv = (const __bf16*)xb_;
    const int tid = threadIdx.x, lane = tid & 63, wv = tid >> 6;
    const int laneh = lane >> 5, lrow = lane & 31;
    const int xcd = blockIdx.x & 7, lin = blockIdx.x >> 3;   // lin 0..127
    const int cs  = xcd * 4 + (lin & 3);                     // 0..31
    const int qg  = lin >> 2;                                // 0..31
    const int qA = qg * 256 + wv * 64 + lrow;
    const int qB = qA + 32;
    const int cbase = cs * CHUNKA;
    const int view = cs * 2 + laneh;

    bf16x8 bfrA[5], bfrB[5];
    {
        const __bf16* bp = xbv + (size_t)qA * KROW + laneh * 8;
#pragma unroll
        for (int s = 0; s < 5; ++s) bfrA[s] = *(const bf16x8*)(bp + s * 16);
        bp += (size_t)32 * KROW;
#pragma unroll
        for (int s = 0; s < 5; ++s) bfrB[s] = *(const bf16x8*)(bp + s * 16);
    }

    float t1a = -FLT_MAX, t1b = -FLT_MAX;

    const __bf16* ap = cbv + (size_t)(cbase + lrow) * KROW + laneh * 8;
    bf16x8 fA[5], fB[5];
#pragma unroll
    for (int s = 0; s < 5; ++s) fA[s] = *(const bf16x8*)(ap + s * 16);
#pragma unroll
    for (int s = 0; s < 5; ++s) fB[s] = *(const bf16x8*)(ap + 32 * KROW + s * 16);
    ap += 64 * KROW;

    for (int it = 0; it < NITERA; it += 2) {
        {   // tile it (fA)
            f32x16 acc = ZERO16;
#pragma unroll
            for (int s = 0; s < 5; ++s)
                acc = __builtin_amdgcn_mfma_f32_32x32x16_bf16(fA[s], bfrA[s], acc, 0, 0, 0);
            t1a = fmaxf(t1a, tmax16(acc));
            f32x16 acc2 = ZERO16;
#pragma unroll
            for (int s = 0; s < 5; ++s)
                acc2 = __builtin_amdgcn_mfma_f32_32x32x16_bf16(fA[s], bfrB[s], acc2, 0, 0, 0);
#pragma unroll
            for (int s = 0; s < 5; ++s) fA[s] = *(const bf16x8*)(ap + s * 16);  // prefetch it+2
            t1b = fmaxf(t1b, tmax16(acc2));
        }
        {   // tile it+1 (fB)
            f32x16 acc = ZERO16;
#pragma unroll
            for (int s = 0; s < 5; ++s)
                acc = __builtin_amdgcn_mfma_f32_32x32x16_bf16(fB[s], bfrA[s], acc, 0, 0, 0);
            t1a = fmaxf(t1a, tmax16(acc));
            f32x16 acc2 = ZERO16;
#pragma unroll
            for (int s = 0; s < 5; ++s)
                acc2 = __builtin_amdgcn_mfma_f32_32x32x16_bf16(fB[s], bfrB[s], acc2, 0, 0, 0);
#pragma unroll
            for (int s = 0; s < 5; ++s) fB[s] = *(const bf16x8*)(ap + 32 * KROW + s * 16); // it+3
            t1b = fmaxf(t1b, tmax16(acc2));
        }
        ap += 64 * KROW;
    }

    top1[(size_t)qA * NVIEWA + view] = t1a;
    top1[(size_t)qB * NVIEWA + view] = t1b;
}

// ---------------- kernel 3: per-query threshold = 8th of 64 view maxima ----
__global__ __launch_bounds__(256) void k_thresh(const float* __restrict__ top1,
                                                float* __restrict__ thrm) {
    const int lane = threadIdx.x & 63;
    const int q = blockIdx.x * 4 + (threadIdx.x >> 6);
    float v = top1[(size_t)q * NVIEWA + lane];
    float mx = -FLT_MAX;
#pragma unroll
    for (int r = 0; r < 8; ++r) {
        mx = v;
#pragma unroll
        for (int off = 32; off; off >>= 1) mx = fmaxf(mx, __shfl_xor(mx, off, 64));
        if (v == mx) v = -FLT_MAX;
    }
    if (lane == 0) thrm[q] = mx - DELTA;
}

// collect epilogue: gate on tile-max, then mask+ctz walk (popcount iters)
__device__ __forceinline__ void coll_ep(const f32x16& acc, float Tm, int code0,
                                        unsigned short* __restrict__ buf, unsigned& c) {
    if (__any(tmax16(acc) >= Tm)) {
        unsigned k = 0;
#pragma unroll
        for (int j = 0; j < 16; ++j) k |= (acc[j] >= Tm) ? (1u << j) : 0u;
        while (k) {
            const int j = __builtin_ctz(k); k &= k - 1;
            if (c < CAP) buf[c] = (unsigned short)(code0 + RJ(j));
            ++c;
        }
    }
}

// ---------------- kernel 4: collect survivors (full codebook) --------------
// grid 1024 = 32 qg x 32 cs (r9/r18-measured optimum: 2048-code chunks).
// XCD swizzle: xcd owns cs in [xcd*4, xcd*4+4) -> 4 x 320 KB = 1.28 MB per
// XCD (L2-resident). r15/r18 register structure (2 buffers, 2 query-sets).
__global__ __launch_bounds__(256, 4) void k_collect(const unsigned short* __restrict__ cbb_,
                                                    const unsigned short* __restrict__ xb_,
                                                    const float* __restrict__ thrm,
                                                    unsigned short* __restrict__ cand,
                                                    unsigned char* __restrict__ cnt) {
    const __bf16* cbv = (const __bf16*)cbb_;
    const __bf16* xbv = (const __bf16*)xb_;
    const int tid = threadIdx.x, lane = tid & 63, wv = tid >> 6;
    const int laneh = lane >> 5, lrow = lane & 31;
    const int xcd = blockIdx.x & 7, lin = blockIdx.x >> 3;   // lin 0..127
    const int cs  = xcd * 4 + (lin & 3);                     // 0..31
    const int qg  = lin >> 2;                                // 0..31
    const int qA = qg * 256 + wv * 64 + lrow;
    const int qB = qA + 32;
    const int cbase = cs * CHUNK;
    const int view = cs * 2 + laneh;

    bf16x8 bfrA[5], bfrB[5];
    {
        const __bf16* bp = xbv + (size_t)qA * KROW + laneh * 8;
#pragma unroll
        for (int s = 0; s < 5; ++s) bfrA[s] = *(const bf16x8*)(bp + s * 16);
        bp += (size_t)32 * KROW;
#pragma unroll
        for (int s = 0; s < 5; ++s) bfrB[s] = *(const bf16x8*)(bp + s * 16);
    }
    const float TmA = thrm[qA];
    const float TmB = thrm[qB];
    unsigned cA = 0, cB = 0;
    unsigned short* bufA = cand + ((size_t)qA * NVIEW + view) * CAP;
    unsigned short* bufB = cand + ((size_t)qB * NVIEW + view) * CAP;

    const __bf16* ap = cbv + (size_t)(cbase + lrow) * KROW + laneh * 8;
    bf16x8 fA[5], fB[5];
#pragma unroll
    for (int s = 0; s < 5; ++s) fA[s] = *(const bf16x8*)(ap + s * 16);
#pragma unroll
    for (int s = 0; s < 5; ++s) fB[s] = *(const bf16x8*)(ap + 32 * KROW + s * 16);
    ap += 64 * KROW;

    for (int it = 0; it < NITER; it += 2) {
        {   // tile it (fA)
            const int code0 = cbase + it * 32 + 4 * laneh;
            f32x16 acc = ZERO16;
#pragma unroll
            for (int s = 0; s < 5; ++s)
                acc = __builtin_amdgcn_mfma_f32_32x32x16_bf16(fA[s], bfrA[s], acc, 0, 0, 0);
            coll_ep(acc, TmA, code0, bufA, cA);
            f32x16 acc2 = ZERO16;
#pragma unroll
            for (int s = 0; s < 5; ++s)
                acc2 = __builtin_amdgcn_mfma_f32_32x32x16_bf16(fA[s], bfrB[s], acc2, 0, 0, 0);
#pragma unroll
            for (int s = 0; s < 5; ++s) fA[s] = *(const bf16x8*)(ap + s * 16);  // prefetch it+2
            coll_ep(acc2, TmB, code0, bufB, cB);
        }
        {   // tile it+1 (fB)
            const int code0 = cbase + (it + 1) * 32 + 4 * laneh;
            f32x16 acc = ZERO16;
#pragma unroll
            for (int s = 0; s < 5; ++s)
                acc = __builtin_amdgcn_mfma_f32_32x32x16_bf16(fB[s], bfrA[s], acc, 0, 0, 0);
            coll_ep(acc, TmA, code0, bufA, cA);
            f32x16 acc2 = ZERO16;
#pragma unroll
            for (int s = 0; s < 5; ++s)
                acc2 = __builtin_amdgcn_mfma_f32_32x32x16_bf16(fB[s], bfrB[s], acc2, 0, 0, 0);
#pragma unroll
            for (int s = 0; s < 5; ++s) fB[s] = *(const bf16x8*)(ap + 32 * KROW + s * 16); // it+3
            coll_ep(acc2, TmB, code0, bufB, cB);
        }
        ap += 64 * KROW;
    }
    cnt[(size_t)qA * NVIEW + view] = (unsigned char)(cA < CAP ? cA : CAP);
    cnt[(size_t)qB * NVIEW + view] = (unsigned char)(cB < CAP ? cB : CAP);
}

// ---- numpy pairwise_sum (n=64 base case), mul/add NOT contracted ----------
__device__ __forceinline__ float np_pairwise_sq64(const float* __restrict__ p) {
    float r[8];
#pragma unroll
    for (int j = 0; j < 8; ++j) r[j] = __fmul_rn(p[j], p[j]);
#pragma unroll
    for (int k = 1; k < 8; ++k)
#pragma unroll
        for (int j = 0; j < 8; ++j)
            r[j] = __fadd_rn(r[j], __fmul_rn(p[8 * k + j], p[8 * k + j]));
    const float t01 = __fadd_rn(r[0], r[1]);
    const float t23 = __fadd_rn(r[2], r[3]);
    const float t45 = __fadd_rn(r[4], r[5]);
    const float t67 = __fadd_rn(r[6], r[7]);
    return __fadd_rn(__fadd_rn(t01, t23), __fadd_rn(t45, t67));
}

// reference-f32 score key: ((2*xc - x2) - c2), xc = sequential fma chain
__device__ __forceinline__ float score_key(const float* __restrict__ xr,
                                           const float* __restrict__ cr,
                                           float x2e) {
    float xc = 0.f;
#pragma unroll
    for (int d = 0; d < DIM; ++d) xc = __builtin_fmaf(cr[d], xr[d], xc);
    const float c2e = np_pairwise_sq64(cr);
    return __fsub_rn(__fsub_rn(__fmul_rn(2.0f, xc), x2e), c2e);
}

// ---------------- kernel 5: exact-f32 rescore of survivors -----------------
// one wave per query; lane = view (64 views) -> prefix-sum -> LDS compact.
// ids written as FLOAT32 VALUES (harness reads whole d_out as f32).
__global__ __launch_bounds__(256) void k_rescore(const float* __restrict__ x,
                                                 const float* __restrict__ cb,
                                                 const unsigned short* __restrict__ cand,
                                                 const unsigned char* __restrict__ cnt,
                                                 float* __restrict__ out0,
                                                 float* __restrict__ out1) {
    __shared__ int s_ids[4][MAXSUR];
    const int lane = threadIdx.x & 63;
    const int wvi = threadIdx.x >> 6;
    const int q = blockIdx.x * 4 + wvi;
    const float* xr = x + ((size_t)q << 6);
    const float x2e = np_pairwise_sq64(xr);

    // lane = view; compact all survivors into LDS
    const int c = cnt[(size_t)q * NVIEW + lane];
    int p = c;
#pragma unroll
    for (int off = 1; off < 64; off <<= 1) {
        const int t = __shfl_up(p, off, 64);
        if (lane >= off) p += t;
    }
    const int excl = p - c;
    int total = __shfl(p, 63, 64);
    if (total > MAXSUR) total = MAXSUR;
    const unsigned short* src = cand + ((size_t)q * NVIEW + lane) * CAP;
    for (int k = 0; k < c; ++k) {
        const int dst = excl + k;
        if (dst < MAXSUR) s_ids[wvi][dst] = src[k];
    }
    __syncthreads();

    float vv[8]; int id[8];
#pragma unroll
    for (int s = 0; s < 8; ++s) {
        vv[s] = -FLT_MAX; id[s] = 1 << 20;
        if (s * 64 < total) {
            const int pos = lane + 64 * s;
            if (pos < total) {
                const int idv = s_ids[wvi][pos];
                id[s] = idv;
                vv[s] = score_key(xr, cb + (size_t)idv * DIM, x2e);
            }
        }
    }

    double accd = 0.0;
#pragma unroll
    for (int rep = 0; rep < KC; ++rep) {
        float bv = vv[0]; int bi = id[0];
#pragma unroll
        for (int s = 1; s < 8; ++s)
            if (vv[s] > bv || (vv[s] == bv && id[s] < bi)) { bv = vv[s]; bi = id[s]; }
#pragma unroll
        for (int off = 32; off; off >>= 1) {
            const float ov = __shfl_xor(bv, off, 64);
            const int   oi = __shfl_xor(bi, off, 64);
            if (ov > bv || (ov == bv && oi < bi)) { bv = ov; bi = oi; }
        }
        if (lane == 0) out1[q * KC + rep] = (float)bi;   // rank-ordered ids
        accd += (double)cb[(size_t)bi * DIM + lane];     // lane = dim
#pragma unroll
        for (int s = 0; s < 8; ++s) if (id[s] == bi) vv[s] = -FLT_MAX;
    }
    out0[(size_t)q * DIM + lane] = (float)(accd * 0.125);
}

// ---------------------------------------------------------------------------
extern "C" void kernel_launch(void* const* d_in, const int* in_sizes, int n_in,
                              void* d_out, int out_size, void* d_ws, size_t ws_size,
                              hipStream_t stream) {
    const float* x  = (const float*)d_in[0];   // [8192][64]
    const float* cb = (const float*)d_in[1];   // [65536][64]

    char* ws = (char*)d_ws;
    unsigned short* cbb  = (unsigned short*)ws;                                   // 10.49 MB
    unsigned short* xb   = (unsigned short*)(ws + (size_t)NCODES * KROW * 2);     // 1.31 MB (absorbs prefetch overrun)
    float*          top1 = (float*)(ws + (size_t)NCODES * KROW * 2
                                       + (size_t)NQ * KROW * 2);                  // 2.10 MB
    float*          thrm = (float*)((char*)top1 + (size_t)NQ * NVIEWA * 4);       // 32 KB
    unsigned char*  cnt  = (unsigned char*)((char*)thrm + (size_t)NQ * 4);        // 512 KB
    unsigned short* cand = (unsigned short*)((char*)cnt + (size_t)NQ * NVIEW);    // 12.58 MB

    float* out0 = (float*)d_out;                       // [8192][64] f32
    float* out1 = (float*)d_out + (size_t)NQ * DIM;    // [8192][8] ids-as-f32

    k_conv   <<<NCODES / 256 + NQ / 256, 256, 0, stream>>>(cb, x, cbb, xb);
    k_scanA  <<<1024,   256, 0, stream>>>(cbb, xb, top1);
    k_thresh <<<NQ / 4, 256, 0, stream>>>(top1, thrm);
    k_collect<<<1024,   256, 0, stream>>>(cbb, xb, thrm, cand, cnt);
    k_rescore<<<NQ / 4, 256, 0, stream>>>(x, cb, cand, cnt, out0, out1);
}

// Round 20
// 175.832 us; speedup vs baseline: 1.0571x; 1.0571x over previous
//
#include <hip/hip_runtime.h>
#include <float.h>

#define DIM     64
#define NCODES  65536
#define KC      8
#define NQ      8192        // B*S
#define KROW    80          // bf16 row: 64 data + c2_hi + c2_lo + zeros (5 mfma k-steps)
#define CS      32          // collect code splits (r9/r18-measured optimum)
#define CHUNK   (NCODES/CS) // 2048 codes per block-scan (collect)
#define NITER   (CHUNK/32)  // 64 tiles
#define NVIEW   64          // collect views per query (CS * 2 lane-halves)
#define CAP     12          // candidate slots per (query,view)
#define DELTA   0.75f       // collect margin: >= 2 * worst bf16-vs-exact score error
#define MAXSUR  512         // rescore capacity (8 x 64)
// pass-A subset: threshold needs only >=8 distinct codes' scores
#define CSA     32          // pass-A chunks
#define CHUNKA  512         // codes per pass-A wave-scan (subset = 16384 codes)
#define NITERA  (CHUNKA/32) // 16 tiles
#define NVIEWA  64          // pass-A views per query (CSA * 2 lane-halves)

typedef __bf16 bf16x8 __attribute__((ext_vector_type(8)));
typedef float  f32x16 __attribute__((ext_vector_type(16)));
typedef unsigned short u16x8 __attribute__((ext_vector_type(8)));

#define ZERO16 {0,0,0,0, 0,0,0,0, 0,0,0,0, 0,0,0,0}

static __device__ __forceinline__ unsigned short f2bf(float f) {
    unsigned u = __float_as_uint(f);
    u += 0x7FFFu + ((u >> 16) & 1u);
    return (unsigned short)(u >> 16);
}

#define RJ(j) (((j) & 3) + 8 * ((j) >> 2))   // C/D row for acc reg j (HW-verified)

// ---------------- kernel 1: fused conversion (codebook + x) ----------------
__global__ __launch_bounds__(256) void k_conv(const float* __restrict__ cb,
                                              const float* __restrict__ x,
                                              unsigned short* __restrict__ cbb,
                                              unsigned short* __restrict__ xb) {
    if (blockIdx.x < NCODES / 256) {
        int n = blockIdx.x * 256 + threadIdx.x;
        const float4* src = (const float4*)(cb + (size_t)n * DIM);
        unsigned short* dst = cbb + (size_t)n * KROW;
        float s = 0.f;
#pragma unroll
        for (int c = 0; c < 8; ++c) {
            float4 f0 = src[2 * c], f1 = src[2 * c + 1];
            s = fmaf(f0.x, f0.x, s); s = fmaf(f0.y, f0.y, s);
            s = fmaf(f0.z, f0.z, s); s = fmaf(f0.w, f0.w, s);
            s = fmaf(f1.x, f1.x, s); s = fmaf(f1.y, f1.y, s);
            s = fmaf(f1.z, f1.z, s); s = fmaf(f1.w, f1.w, s);
            u16x8 o;
            o[0] = f2bf(2.f * f0.x); o[1] = f2bf(2.f * f0.y);
            o[2] = f2bf(2.f * f0.z); o[3] = f2bf(2.f * f0.w);
            o[4] = f2bf(2.f * f1.x); o[5] = f2bf(2.f * f1.y);
            o[6] = f2bf(2.f * f1.z); o[7] = f2bf(2.f * f1.w);
            *(u16x8*)(dst + c * 8) = o;
        }
        unsigned short hi = f2bf(s);
        float hif = __uint_as_float(((unsigned)hi) << 16);
        unsigned short lo = f2bf(s - hif);
        u16x8 p = { (unsigned short)(hi ^ 0x8000u), (unsigned short)(lo ^ 0x8000u),
                    0, 0, 0, 0, 0, 0 };
        *(u16x8*)(dst + 64) = p;
        u16x8 z = {0, 0, 0, 0, 0, 0, 0, 0};
        *(u16x8*)(dst + 72) = z;
    } else {
        int n = (blockIdx.x - NCODES / 256) * 256 + threadIdx.x;
        const float4* src = (const float4*)(x + (size_t)n * DIM);
        unsigned short* dst = xb + (size_t)n * KROW;
#pragma unroll
        for (int c = 0; c < 8; ++c) {
            float4 f0 = src[2 * c], f1 = src[2 * c + 1];
            u16x8 o;
            o[0] = f2bf(f0.x); o[1] = f2bf(f0.y); o[2] = f2bf(f0.z); o[3] = f2bf(f0.w);
            o[4] = f2bf(f1.x); o[5] = f2bf(f1.y); o[6] = f2bf(f1.z); o[7] = f2bf(f1.w);
            *(u16x8*)(dst + c * 8) = o;
        }
        u16x8 p = {0x3F80u, 0x3F80u, 0, 0, 0, 0, 0, 0};   // 1.0, 1.0
        *(u16x8*)(dst + 64) = p;
        u16x8 z = {0, 0, 0, 0, 0, 0, 0, 0};
        *(u16x8*)(dst + 72) = z;
    }
}

// max of 16 acc values, nested-triple form so clang fuses to v_max3 (8 ops)
__device__ __forceinline__ float tmax16(const f32x16& a) {
    const float m0 = fmaxf(fmaxf(a[0],  a[1]),  a[2]);
    const float m1 = fmaxf(fmaxf(a[3],  a[4]),  a[5]);
    const float m2 = fmaxf(fmaxf(a[6],  a[7]),  a[8]);
    const float m3 = fmaxf(fmaxf(a[9],  a[10]), a[11]);
    const float m4 = fmaxf(fmaxf(a[12], a[13]), a[14]);
    const float n0 = fmaxf(fmaxf(m0, m1), m2);
    const float n1 = fmaxf(fmaxf(m3, m4), a[15]);
    return fmaxf(n0, n1);
}

// ---------------- kernel 2: pass A — per-view top-1 on a 16K-code subset ---
// grid 1024. XCD swizzle: all same-chunk blocks on one XCD (chunk L2-resident).
// r15 register structure (2 buffers, 2 query-sets, launch_bounds(,4)).
// THRESHOLD SAFETY: T = 8th-best of 64 DISJOINT views' maxima = 8th-best of
// >=8 distinct codes' bf16 scores => T <= g_s8(global) <= f_s8 + eps. Any
// exact-top-8 member m has g(m) >= f_s8 - eps >= T - 2eps; DELTA >= 2eps.
__global__ __launch_bounds__(256, 4) void k_scanA(const unsigned short* __restrict__ cbb_,
                                                  const unsigned short* __restrict__ xb_,
                                                  float* __restrict__ top1) {
    const __bf16* cbv = (const __bf16*)cbb_;
    const __bf16* xbv = (const __bf16*)xb_;
    const int tid = threadIdx.x, lane = tid & 63, wv = tid >> 6;
    const int laneh = lane >> 5, lrow = lane & 31;
    const int xcd = blockIdx.x & 7, lin = blockIdx.x >> 3;   // lin 0..127
    const int cs  = xcd * 4 + (lin & 3);                     // 0..31
    const int qg  = lin >> 2;                                // 0..31
    const int qA = qg * 256 + wv * 64 + lrow;
    const int qB = qA + 32;
    const int cbase = cs * CHUNKA;
    const int view = cs * 2 + laneh;

    bf16x8 bfrA[5], bfrB[5];
    {
        const __bf16* bp = xbv + (size_t)qA * KROW + laneh * 8;
#pragma unroll
        for (int s = 0; s < 5; ++s) bfrA[s] = *(const bf16x8*)(bp + s * 16);
        bp += (size_t)32 * KROW;
#pragma unroll
        for (int s = 0; s < 5; ++s) bfrB[s] = *(const bf16x8*)(bp + s * 16);
    }

    float t1a = -FLT_MAX, t1b = -FLT_MAX;

    const __bf16* ap = cbv + (size_t)(cbase + lrow) * KROW + laneh * 8;
    bf16x8 fA[5], fB[5];
#pragma unroll
    for (int s = 0; s < 5; ++s) fA[s] = *(const bf16x8*)(ap + s * 16);
#pragma unroll
    for (int s = 0; s < 5; ++s) fB[s] = *(const bf16x8*)(ap + 32 * KROW + s * 16);
    ap += 64 * KROW;

    for (int it = 0; it < NITERA; it += 2) {
        {   // tile it (fA)
            f32x16 acc = ZERO16;
#pragma unroll
            for (int s = 0; s < 5; ++s)
                acc = __builtin_amdgcn_mfma_f32_32x32x16_bf16(fA[s], bfrA[s], acc, 0, 0, 0);
            t1a = fmaxf(t1a, tmax16(acc));
            f32x16 acc2 = ZERO16;
#pragma unroll
            for (int s = 0; s < 5; ++s)
                acc2 = __builtin_amdgcn_mfma_f32_32x32x16_bf16(fA[s], bfrB[s], acc2, 0, 0, 0);
#pragma unroll
            for (int s = 0; s < 5; ++s) fA[s] = *(const bf16x8*)(ap + s * 16);  // prefetch it+2
            t1b = fmaxf(t1b, tmax16(acc2));
        }
        {   // tile it+1 (fB)
            f32x16 acc = ZERO16;
#pragma unroll
            for (int s = 0; s < 5; ++s)
                acc = __builtin_amdgcn_mfma_f32_32x32x16_bf16(fB[s], bfrA[s], acc, 0, 0, 0);
            t1a = fmaxf(t1a, tmax16(acc));
            f32x16 acc2 = ZERO16;
#pragma unroll
            for (int s = 0; s < 5; ++s)
                acc2 = __builtin_amdgcn_mfma_f32_32x32x16_bf16(fB[s], bfrB[s], acc2, 0, 0, 0);
#pragma unroll
            for (int s = 0; s < 5; ++s) fB[s] = *(const bf16x8*)(ap + 32 * KROW + s * 16); // it+3
            t1b = fmaxf(t1b, tmax16(acc2));
        }
        ap += 64 * KROW;
    }

    top1[(size_t)qA * NVIEWA + view] = t1a;
    top1[(size_t)qB * NVIEWA + view] = t1b;
}

// ---------------- kernel 3: per-query threshold = 8th of 64 view maxima ----
__global__ __launch_bounds__(256) void k_thresh(const float* __restrict__ top1,
                                                float* __restrict__ thrm) {
    const int lane = threadIdx.x & 63;
    const int q = blockIdx.x * 4 + (threadIdx.x >> 6);
    float v = top1[(size_t)q * NVIEWA + lane];
    float mx = -FLT_MAX;
#pragma unroll
    for (int r = 0; r < 8; ++r) {
        mx = v;
#pragma unroll
        for (int off = 32; off; off >>= 1) mx = fmaxf(mx, __shfl_xor(mx, off, 64));
        if (v == mx) v = -FLT_MAX;
    }
    if (lane == 0) thrm[q] = mx - DELTA;
}

// collect epilogue: gate on tile-max, then mask+ctz walk (popcount iters)
__device__ __forceinline__ void coll_ep(const f32x16& acc, float Tm, int code0,
                                        unsigned short* __restrict__ buf, unsigned& c) {
    if (__any(tmax16(acc) >= Tm)) {
        unsigned k = 0;
#pragma unroll
        for (int j = 0; j < 16; ++j) k |= (acc[j] >= Tm) ? (1u << j) : 0u;
        while (k) {
            const int j = __builtin_ctz(k); k &= k - 1;
            if (c < CAP) buf[c] = (unsigned short)(code0 + RJ(j));
            ++c;
        }
    }
}

// ---------------- kernel 4: collect survivors (full codebook) --------------
// grid 1024 = 32 qg x 32 cs (r9/r18-measured optimum: 2048-code chunks).
// XCD swizzle: xcd owns cs in [xcd*4, xcd*4+4) -> 4 x 320 KB = 1.28 MB per
// XCD (L2-resident). r15/r18 register structure (2 buffers, 2 query-sets).
__global__ __launch_bounds__(256, 4) void k_collect(const unsigned short* __restrict__ cbb_,
                                                    const unsigned short* __restrict__ xb_,
                                                    const float* __restrict__ thrm,
                                                    unsigned short* __restrict__ cand,
                                                    unsigned char* __restrict__ cnt) {
    const __bf16* cbv = (const __bf16*)cbb_;
    const __bf16* xbv = (const __bf16*)xb_;
    const int tid = threadIdx.x, lane = tid & 63, wv = tid >> 6;
    const int laneh = lane >> 5, lrow = lane & 31;
    const int xcd = blockIdx.x & 7, lin = blockIdx.x >> 3;   // lin 0..127
    const int cs  = xcd * 4 + (lin & 3);                     // 0..31
    const int qg  = lin >> 2;                                // 0..31
    const int qA = qg * 256 + wv * 64 + lrow;
    const int qB = qA + 32;
    const int cbase = cs * CHUNK;
    const int view = cs * 2 + laneh;

    bf16x8 bfrA[5], bfrB[5];
    {
        const __bf16* bp = xbv + (size_t)qA * KROW + laneh * 8;
#pragma unroll
        for (int s = 0; s < 5; ++s) bfrA[s] = *(const bf16x8*)(bp + s * 16);
        bp += (size_t)32 * KROW;
#pragma unroll
        for (int s = 0; s < 5; ++s) bfrB[s] = *(const bf16x8*)(bp + s * 16);
    }
    const float TmA = thrm[qA];
    const float TmB = thrm[qB];
    unsigned cA = 0, cB = 0;
    unsigned short* bufA = cand + ((size_t)qA * NVIEW + view) * CAP;
    unsigned short* bufB = cand + ((size_t)qB * NVIEW + view) * CAP;

    const __bf16* ap = cbv + (size_t)(cbase + lrow) * KROW + laneh * 8;
    bf16x8 fA[5], fB[5];
#pragma unroll
    for (int s = 0; s < 5; ++s) fA[s] = *(const bf16x8*)(ap + s * 16);
#pragma unroll
    for (int s = 0; s < 5; ++s) fB[s] = *(const bf16x8*)(ap + 32 * KROW + s * 16);
    ap += 64 * KROW;

    for (int it = 0; it < NITER; it += 2) {
        {   // tile it (fA)
            const int code0 = cbase + it * 32 + 4 * laneh;
            f32x16 acc = ZERO16;
#pragma unroll
            for (int s = 0; s < 5; ++s)
                acc = __builtin_amdgcn_mfma_f32_32x32x16_bf16(fA[s], bfrA[s], acc, 0, 0, 0);
            coll_ep(acc, TmA, code0, bufA, cA);
            f32x16 acc2 = ZERO16;
#pragma unroll
            for (int s = 0; s < 5; ++s)
                acc2 = __builtin_amdgcn_mfma_f32_32x32x16_bf16(fA[s], bfrB[s], acc2, 0, 0, 0);
#pragma unroll
            for (int s = 0; s < 5; ++s) fA[s] = *(const bf16x8*)(ap + s * 16);  // prefetch it+2
            coll_ep(acc2, TmB, code0, bufB, cB);
        }
        {   // tile it+1 (fB)
            const int code0 = cbase + (it + 1) * 32 + 4 * laneh;
            f32x16 acc = ZERO16;
#pragma unroll
            for (int s = 0; s < 5; ++s)
                acc = __builtin_amdgcn_mfma_f32_32x32x16_bf16(fB[s], bfrA[s], acc, 0, 0, 0);
            coll_ep(acc, TmA, code0, bufA, cA);
            f32x16 acc2 = ZERO16;
#pragma unroll
            for (int s = 0; s < 5; ++s)
                acc2 = __builtin_amdgcn_mfma_f32_32x32x16_bf16(fB[s], bfrB[s], acc2, 0, 0, 0);
#pragma unroll
            for (int s = 0; s < 5; ++s) fB[s] = *(const bf16x8*)(ap + 32 * KROW + s * 16); // it+3
            coll_ep(acc2, TmB, code0, bufB, cB);
        }
        ap += 64 * KROW;
    }
    cnt[(size_t)qA * NVIEW + view] = (unsigned char)(cA < CAP ? cA : CAP);
    cnt[(size_t)qB * NVIEW + view] = (unsigned char)(cB < CAP ? cB : CAP);
}

// ---- numpy pairwise_sum (n=64 base case), mul/add NOT contracted ----------
__device__ __forceinline__ float np_pairwise_sq64(const float* __restrict__ p) {
    float r[8];
#pragma unroll
    for (int j = 0; j < 8; ++j) r[j] = __fmul_rn(p[j], p[j]);
#pragma unroll
    for (int k = 1; k < 8; ++k)
#pragma unroll
        for (int j = 0; j < 8; ++j)
            r[j] = __fadd_rn(r[j], __fmul_rn(p[8 * k + j], p[8 * k + j]));
    const float t01 = __fadd_rn(r[0], r[1]);
    const float t23 = __fadd_rn(r[2], r[3]);
    const float t45 = __fadd_rn(r[4], r[5]);
    const float t67 = __fadd_rn(r[6], r[7]);
    return __fadd_rn(__fadd_rn(t01, t23), __fadd_rn(t45, t67));
}

// reference-f32 score key: ((2*xc - x2) - c2), xc = sequential fma chain
__device__ __forceinline__ float score_key(const float* __restrict__ xr,
                                           const float* __restrict__ cr,
                                           float x2e) {
    float xc = 0.f;
#pragma unroll
    for (int d = 0; d < DIM; ++d) xc = __builtin_fmaf(cr[d], xr[d], xc);
    const float c2e = np_pairwise_sq64(cr);
    return __fsub_rn(__fsub_rn(__fmul_rn(2.0f, xc), x2e), c2e);
}

// ---------------- kernel 5: exact-f32 rescore of survivors -----------------
// one wave per query; lane = view (64 views) -> prefix-sum -> LDS compact.
// ids written as FLOAT32 VALUES (harness reads whole d_out as f32).
__global__ __launch_bounds__(256) void k_rescore(const float* __restrict__ x,
                                                 const float* __restrict__ cb,
                                                 const unsigned short* __restrict__ cand,
                                                 const unsigned char* __restrict__ cnt,
                                                 float* __restrict__ out0,
                                                 float* __restrict__ out1) {
    __shared__ int s_ids[4][MAXSUR];
    const int lane = threadIdx.x & 63;
    const int wvi = threadIdx.x >> 6;
    const int q = blockIdx.x * 4 + wvi;
    const float* xr = x + ((size_t)q << 6);
    const float x2e = np_pairwise_sq64(xr);

    // lane = view; compact all survivors into LDS
    const int c = cnt[(size_t)q * NVIEW + lane];
    int p = c;
#pragma unroll
    for (int off = 1; off < 64; off <<= 1) {
        const int t = __shfl_up(p, off, 64);
        if (lane >= off) p += t;
    }
    const int excl = p - c;
    int total = __shfl(p, 63, 64);
    if (total > MAXSUR) total = MAXSUR;
    const unsigned short* src = cand + ((size_t)q * NVIEW + lane) * CAP;
    for (int k = 0; k < c; ++k) {
        const int dst = excl + k;
        if (dst < MAXSUR) s_ids[wvi][dst] = src[k];
    }
    __syncthreads();

    float vv[8]; int id[8];
#pragma unroll
    for (int s = 0; s < 8; ++s) {
        vv[s] = -FLT_MAX; id[s] = 1 << 20;
        if (s * 64 < total) {
            const int pos = lane + 64 * s;
            if (pos < total) {
                const int idv = s_ids[wvi][pos];
                id[s] = idv;
                vv[s] = score_key(xr, cb + (size_t)idv * DIM, x2e);
            }
        }
    }

    double accd = 0.0;
#pragma unroll
    for (int rep = 0; rep < KC; ++rep) {
        float bv = vv[0]; int bi = id[0];
#pragma unroll
        for (int s = 1; s < 8; ++s)
            if (vv[s] > bv || (vv[s] == bv && id[s] < bi)) { bv = vv[s]; bi = id[s]; }
#pragma unroll
        for (int off = 32; off; off >>= 1) {
            const float ov = __shfl_xor(bv, off, 64);
            const int   oi = __shfl_xor(bi, off, 64);
            if (ov > bv || (ov == bv && oi < bi)) { bv = ov; bi = oi; }
        }
        if (lane == 0) out1[q * KC + rep] = (float)bi;   // rank-ordered ids
        accd += (double)cb[(size_t)bi * DIM + lane];     // lane = dim
#pragma unroll
        for (int s = 0; s < 8; ++s) if (id[s] == bi) vv[s] = -FLT_MAX;
    }
    out0[(size_t)q * DIM + lane] = (float)(accd * 0.125);
}

// ---------------------------------------------------------------------------
extern "C" void kernel_launch(void* const* d_in, const int* in_sizes, int n_in,
                              void* d_out, int out_size, void* d_ws, size_t ws_size,
                              hipStream_t stream) {
    const float* x  = (const float*)d_in[0];   // [8192][64]
    const float* cb = (const float*)d_in[1];   // [65536][64]

    char* ws = (char*)d_ws;
    unsigned short* cbb  = (unsigned short*)ws;                                   // 10.49 MB
    unsigned short* xb   = (unsigned short*)(ws + (size_t)NCODES * KROW * 2);     // 1.31 MB (absorbs prefetch overrun)
    float*          top1 = (float*)(ws + (size_t)NCODES * KROW * 2
                                       + (size_t)NQ * KROW * 2);                  // 2.10 MB
    float*          thrm = (float*)((char*)top1 + (size_t)NQ * NVIEWA * 4);       // 32 KB
    unsigned char*  cnt  = (unsigned char*)((char*)thrm + (size_t)NQ * 4);        // 512 KB
    unsigned short* cand = (unsigned short*)((char*)cnt + (size_t)NQ * NVIEW);    // 12.58 MB

    float* out0 = (float*)d_out;                       // [8192][64] f32
    float* out1 = (float*)d_out + (size_t)NQ * DIM;    // [8192][8] ids-as-f32

    k_conv   <<<NCODES / 256 + NQ / 256, 256, 0, stream>>>(cb, x, cbb, xb);
    k_scanA  <<<1024,   256, 0, stream>>>(cbb, xb, top1);
    k_thresh <<<NQ / 4, 256, 0, stream>>>(top1, thrm);
    k_collect<<<1024,   256, 0, stream>>>(cbb, xb, thrm, cand, cnt);
    k_rescore<<<NQ / 4, 256, 0, stream>>>(x, cb, cand, cnt, out0, out1);
}